// Round 1
// baseline (870.874 us; speedup 1.0000x reference)
//
#include <hip/hip_runtime.h>
#include <hip/hip_fp16.h>

typedef _Float16 h2 __attribute__((ext_vector_type(2)));
typedef _Float16 h8 __attribute__((ext_vector_type(8)));
typedef float f4 __attribute__((ext_vector_type(4)));
typedef float f4v __attribute__((ext_vector_type(4)));

#define NB 128
#define NT 512
#define ND 256
#define NU 256

// ---------- helpers ----------
__device__ __forceinline__ float fdot2f(h2 a, h2 b, float c) {
#if __has_builtin(__builtin_amdgcn_fdot2)
  return __builtin_amdgcn_fdot2(a, b, c, false);
#else
  return c + (float)a[0] * (float)b[0] + (float)a[1] * (float)b[1];
#endif
}

__device__ __forceinline__ h2 pick2(h8 v, int j) {
  h2 r;
  r[0] = v[2 * j];
  r[1] = v[2 * j + 1];
  return r;
}

__device__ __forceinline__ float fast_rcp(float x) {
  return __builtin_amdgcn_rcpf(x);
}

// ---------- kernel 1: weight transpose + fp16 convert ----------
// WT[g][u][k]  = W_g[k][u]      (x part, k in [0,256))
// WhT[g][u][k] = W_g[256+k][u]  (h part)
__global__ void k_prep(const float* __restrict__ Wr, const float* __restrict__ Wz,
                       const float* __restrict__ Wc, _Float16* __restrict__ WT,
                       _Float16* __restrict__ WhT) {
  int idx = blockIdx.x * 256 + threadIdx.x;  // 0 .. 3*256*256-1
  int g = idx >> 16;
  int r = idx & 65535;
  int u = r >> 8;
  int k = r & 255;
  const float* W = (g == 0) ? Wr : ((g == 1) ? Wz : Wc);
  WT[idx]  = (_Float16)W[k * NU + u];
  WhT[idx] = (_Float16)W[(ND + k) * NU + u];
}

// ---------- kernel 2: gx[bt][g*256+u] = x[bt] @ Wx_g + b_g  (fp16 out) ----------
#define BM 128
#define BN 128
#define BK 32
#define LDT 40  // padded LDS stride (fp16 elems)

__global__ __launch_bounds__(256) void k_gemm(const float* __restrict__ x,
                                              const _Float16* __restrict__ WT,
                                              const float* __restrict__ br,
                                              const float* __restrict__ bz,
                                              const float* __restrict__ bc,
                                              _Float16* __restrict__ gx) {
  __shared__ alignas(16) _Float16 Al[BM * LDT];
  __shared__ alignas(16) _Float16 Bl[BN * LDT];
  const int n0 = blockIdx.x * BN;  // 0..5 tiles over N=768
  const int m0 = blockIdx.y * BM;  // 0..511 tiles over M=65536
  const int tid = threadIdx.x;
  const int lane = tid & 63;
  const int wid = tid >> 6;
  const int mb = (wid >> 1) * 64;
  const int nb = (wid & 1) * 64;

  f4 acc[4][4] = {};

  for (int k0 = 0; k0 < 256; k0 += BK) {
    __syncthreads();
    // ---- stage A (x, f32 -> fp16): 128 rows x 32 k
    {
      int row = tid >> 1;
      int seg = (tid & 1) * 16;
      const float* src = x + (size_t)(m0 + row) * ND + k0 + seg;
      f4v f0 = *(const f4v*)(src);
      f4v f1 = *(const f4v*)(src + 4);
      f4v f2 = *(const f4v*)(src + 8);
      f4v f3 = *(const f4v*)(src + 12);
      h8 w0, w1;
#pragma unroll
      for (int j = 0; j < 4; j++) {
        w0[j] = (_Float16)f0[j];
        w0[4 + j] = (_Float16)f1[j];
        w1[j] = (_Float16)f2[j];
        w1[4 + j] = (_Float16)f3[j];
      }
      *(h8*)&Al[row * LDT + seg] = w0;
      *(h8*)&Al[row * LDT + seg + 8] = w1;
    }
    // ---- stage B (WT fp16, already [n][k]): 128 rows x 32 k
    {
      int row = tid >> 1;
      int seg = (tid & 1) * 16;
      const _Float16* src = WT + (size_t)(n0 + row) * 256 + k0 + seg;
      h8 w0 = *(const h8*)(src);
      h8 w1 = *(const h8*)(src + 8);
      *(h8*)&Bl[row * LDT + seg] = w0;
      *(h8*)&Bl[row * LDT + seg + 8] = w1;
    }
    __syncthreads();
    // ---- compute: 4x4 frags of 16x16, K=32 per iter
    h8 af[4], bf[4];
#pragma unroll
    for (int mt = 0; mt < 4; mt++)
      af[mt] = *(const h8*)&Al[(mb + mt * 16 + (lane & 15)) * LDT + (lane >> 4) * 8];
#pragma unroll
    for (int nt = 0; nt < 4; nt++)
      bf[nt] = *(const h8*)&Bl[(nb + nt * 16 + (lane & 15)) * LDT + (lane >> 4) * 8];
#pragma unroll
    for (int mt = 0; mt < 4; mt++)
#pragma unroll
      for (int nt = 0; nt < 4; nt++)
        acc[mt][nt] = __builtin_amdgcn_mfma_f32_16x16x32_f16(af[mt], bf[nt], acc[mt][nt], 0, 0, 0);
  }

  // ---- epilogue: add bias, store fp16
  const float* bias = (n0 < 256) ? br : ((n0 < 512) ? bz : bc);
#pragma unroll
  for (int nt = 0; nt < 4; nt++) {
    int col = nb + nt * 16 + (lane & 15);
    float bv = bias[(n0 + col) & 255];
#pragma unroll
    for (int mt = 0; mt < 4; mt++) {
#pragma unroll
      for (int r = 0; r < 4; r++) {
        int row = mb + mt * 16 + (lane >> 4) * 4 + r;
        float v = acc[mt][nt][r] + bv;
        gx[(size_t)(m0 + row) * 768 + n0 + col] = (_Float16)v;
      }
    }
  }
}

// ---------- kernel 3: the recurrence. 1 block = 1 batch element ----------
// 512 threads: u = tid&255, half = tid>>8.
//   half=0 thread u: owns r-column u  + c-column u, k in [0,128)
//   half=1 thread u: owns z-column u  + c-column u, k in [128,256)
__global__ __launch_bounds__(512, 2) void k_gru(const float* __restrict__ h0,
                                                const _Float16* __restrict__ WhT,
                                                const _Float16* __restrict__ gx,
                                                float* __restrict__ out) {
  __shared__ alignas(16) _Float16 h16[NU];
  __shared__ alignas(16) float h32[NU];
  __shared__ alignas(16) _Float16 rh16[NU];
  __shared__ alignas(16) float zls[NU];
  __shared__ alignas(16) float cpart[512];

  const int b = blockIdx.x;
  const int tid = threadIdx.x;
  const int u = tid & 255;
  const int half = tid >> 8;

  // ---- load weight columns into registers (fp16, packed pairs)
  h2 wrz[128];  // r (half=0) or z (half=1) column of unit u: 256 fp16
#pragma unroll
  for (int i = 0; i < 32; i++) {
    h8 w = *(const h8*)(WhT + ((size_t)(half * 256 + u)) * 256 + i * 8);
#pragma unroll
    for (int j = 0; j < 4; j++) wrz[i * 4 + j] = pick2(w, j);
  }
  h2 wc[64];  // half of c column u: 128 fp16
#pragma unroll
  for (int i = 0; i < 16; i++) {
    h8 w = *(const h8*)(WhT + ((size_t)(2 * 256 + u)) * 256 + half * 128 + i * 8);
#pragma unroll
    for (int j = 0; j < 4; j++) wc[i * 4 + j] = pick2(w, j);
  }

  if (tid < NU) {
    float h = h0[(size_t)b * NU + tid];
    h32[tid] = h;
    h16[tid] = (_Float16)h;
  }
  __syncthreads();

  const _Float16* gb = gx + (size_t)b * NT * 768;
  float ga = (float)gb[half * 256 + u];  // t=0: r- or z- x-part (bias folded)
  float gc = (float)gb[512 + u];         // t=0: c x-part

  for (int t = 0; t < NT; t++) {
    // prefetch next step's x-parts (used at the very end of this iteration)
    int tn = (t + 1 < NT) ? t + 1 : t;
    _Float16 nga = gb[(size_t)tn * 768 + half * 256 + u];
    _Float16 ngc = gb[(size_t)tn * 768 + 512 + u];

    // ---- phase 1: r/z preactivation = h . wrz + ga
    float a0 = 0.f, a1 = 0.f, a2 = 0.f, a3 = 0.f;
#pragma unroll
    for (int kk = 0; kk < 32; kk++) {
      h8 hv = *(const h8*)&h16[kk * 8];
      a0 = fdot2f(pick2(hv, 0), wrz[kk * 4 + 0], a0);
      a1 = fdot2f(pick2(hv, 1), wrz[kk * 4 + 1], a1);
      a2 = fdot2f(pick2(hv, 2), wrz[kk * 4 + 2], a2);
      a3 = fdot2f(pick2(hv, 3), wrz[kk * 4 + 3], a3);
    }
    float pre = (a0 + a1) + (a2 + a3) + ga;
    float e = __expf(-pre);
    float s = fast_rcp(1.f + e);  // sigmoid
    if (half == 0) {
      rh16[u] = (_Float16)(s * h32[u]);  // r * h
    } else {
      zls[u] = s;  // z
    }
    __syncthreads();

    // ---- phase 2: partial c dot over this thread's k-half
    float c0 = 0.f, c1 = 0.f;
#pragma unroll
    for (int kk = 0; kk < 16; kk++) {
      h8 hv = *(const h8*)&rh16[half * 128 + kk * 8];
      c0 = fdot2f(pick2(hv, 0), wc[kk * 4 + 0], c0);
      c1 = fdot2f(pick2(hv, 1), wc[kk * 4 + 1], c1);
      c0 = fdot2f(pick2(hv, 2), wc[kk * 4 + 2], c0);
      c1 = fdot2f(pick2(hv, 3), wc[kk * 4 + 3], c1);
    }
    cpart[tid] = c0 + c1;
    __syncthreads();

    // ---- phase 3: combine, tanh, h update, write out
    if (half == 0) {
      float pc = cpart[u] + cpart[256 + u] + gc;
      pc = fminf(fmaxf(pc, -15.f), 15.f);
      float e2 = __expf(2.f * pc);
      float c = (e2 - 1.f) * fast_rcp(e2 + 1.f);  // tanh
      float z = zls[u];
      float h = h32[u];
      float hn = h + z * (c - h);
      h32[u] = hn;
      h16[u] = (_Float16)hn;
      out[((size_t)b * NT + t) * NU + u] = hn;
    }
    ga = (float)nga;
    gc = (float)ngc;
    __syncthreads();
  }
}

// ---------- launch ----------
extern "C" void kernel_launch(void* const* d_in, const int* in_sizes, int n_in,
                              void* d_out, int out_size, void* d_ws, size_t ws_size,
                              hipStream_t stream) {
  (void)in_sizes; (void)n_in; (void)out_size; (void)ws_size;
  const float* x  = (const float*)d_in[0];
  const float* h0 = (const float*)d_in[1];
  const float* Wr = (const float*)d_in[2];
  const float* br = (const float*)d_in[3];
  const float* Wz = (const float*)d_in[4];
  const float* bz = (const float*)d_in[5];
  const float* Wc = (const float*)d_in[6];
  const float* bc = (const float*)d_in[7];
  float* out = (float*)d_out;

  _Float16* gx  = (_Float16*)d_ws;            // 128*512*768 fp16 = 96 MB
  _Float16* WT  = gx + (size_t)NB * NT * 768; // 3*256*256 fp16
  _Float16* WhT = WT + 3 * 256 * 256;         // 3*256*256 fp16

  k_prep<<<768, 256, 0, stream>>>(Wr, Wz, Wc, WT, WhT);
  k_gemm<<<dim3(6, 512), 256, 0, stream>>>(x, WT, br, bz, bc, gx);
  k_gru<<<NB, 512, 0, stream>>>(h0, WhT, gx, out);
}